// Round 1
// baseline (2037.048 us; speedup 1.0000x reference)
//
#include <hip/hip_runtime.h>
#include <math.h>

#define NUMR 11
#define NSTEP 64
#define BATCH 8192
#define PDIM 128
#define MC 10000
#define DT (1.0f/64.0f)
#define RDOM 5.0f
#define CAP_EPS 0.1f

// workspace float offsets
#define OFF_HIST 0              // 220 ints
#define OFF_MCJ  256            // 11*128
#define OFF_W3E  1664           // 64*64*6*11 = 270336
#define OFF_B3E  272000         // 64*6*11 = 4224
#define OFF_BT   276224         // 64*64*20*11 = 901120
#define OFF_BB   1177344        // 64*20*11 = 14080
#define OFF_CT   1191424        // 64*64*11 = 45056
#define OFF_BC   1236480        // 64*11 = 704
#define OFF_PART 1237184        // 8*8192 = 65536  -> end 1302720 floats (~5.2MB)

__device__ __forceinline__ float tanh_f(float x) {
    float e = __expf(2.0f * x);
    return 1.0f - 2.0f / (e + 1.0f);
}

__device__ __forceinline__ void reflect3(float* p, float* g) {
    float nr = sqrtf(p[0]*p[0] + p[1]*p[1] + p[2]*p[2]);
    if (nr > RDOM) {
        float inv = 1.0f / fmaxf(nr, 1e-12f);
        float nb0 = p[0]*inv, nb1 = p[1]*inv, nb2 = p[2]*inv;
        float sc = 2.0f*RDOM - nr;
        p[0] = nb0*sc; p[1] = nb1*sc; p[2] = nb2*sc;
        #pragma unroll
        for (int j = 0; j < 3; ++j) {
            float proj = nb0*g[j] + nb1*g[3+j] + nb2*g[6+j];
            g[j]   -= 2.0f*nb0*proj;
            g[3+j] -= 2.0f*nb1*proj;
            g[6+j] -= 2.0f*nb2*proj;
        }
    }
}

// ---- K1: histogram of MC jump sizes per (r, sign*10+a) -------------------
__global__ void k_hist(const float* __restrict__ mcu, const float* __restrict__ jm,
                       int* hist) {
    __shared__ int lh[220];
    int tid = threadIdx.x;
    for (int i = tid; i < 220; i += 256) lh[i] = 0;
    __syncthreads();
    int i = blockIdx.x * 256 + tid;
    if (i < MC * NUMR) {
        int r = i % NUMR;
        float u = mcu[i];
        int cnt = 0;
        #pragma unroll
        for (int j = 0; j < 20; ++j) cnt += (u < jm[r*20 + j]) ? 1 : 0;
        int ind = 20 - cnt;
        int s = (ind < 10) ? (ind + 1) : -(ind - 9);
        int sa = (s > 0) ? (s - 1) : (10 + (-s - 1));
        atomicAdd(&lh[r*20 + sa], 1);
    }
    __syncthreads();
    for (int q = tid; q < 220; q += 256) if (lh[q]) atomicAdd(&hist[q], lh[q]);
}

// ---- K2: mc_jump[r][p] ----------------------------------------------------
__global__ void k_mcj(const int* hist, const float* __restrict__ jl,
                      const float* __restrict__ cr, float* mcj) {
    int i = blockIdx.x * 256 + threadIdx.x;
    if (i >= NUMR * PDIM) return;
    int r = i / PDIM, p = i % PDIM;
    float acc = 0.f;
    #pragma unroll
    for (int sa = 0; sa < 20; ++sa)
        acc += (float)hist[r*20 + sa] * jl[sa*PDIM + p];
    mcj[r*PDIM + p] = acc * cr[r] * (1.0f / (float)MC);
}

// ---- K3: per-step contraction tables -------------------------------------
__global__ void k_tables(const float* __restrict__ W3, const float* __restrict__ b3,
                         const float* __restrict__ emb, const float* __restrict__ Wf3,
                         const float* __restrict__ bf3, const float* __restrict__ jump_r,
                         const float* __restrict__ jl, const float* __restrict__ mcj,
                         float* ws) {
    int t  = blockIdx.x / 65;
    int kk = blockIdx.x % 65;
    bool brow = (kk == 64);
    const float* w3row = brow ? (b3 + t*768) : (W3 + (t*64 + kk)*768);
    const float* wfrow = brow ? (bf3 + t*128) : (Wf3 + (t*64 + kk)*128);
    for (int q = threadIdx.x; q < 297; q += blockDim.x) {
        if (q < 66) {
            int o = q / 11, r = q % 11;
            const float* e = emb + (t*11 + r)*128;
            float acc = 0.f;
            for (int p = 0; p < 128; ++p) acc += e[p] * w3row[p*6 + o];
            if (brow) ws[OFF_B3E + (t*6 + o)*11 + r] = acc;
            else      ws[OFF_W3E + ((t*64 + kk)*6 + o)*11 + r] = acc;
        } else if (q < 77) {
            int r = q - 66;
            float acc = 0.f;
            for (int p = 0; p < 128; ++p)
                acc += wfrow[p] * jump_r[r*128 + p] * mcj[r*128 + p];
            if (brow) ws[OFF_BC + t*11 + r] = acc;
            else      ws[OFF_CT + (t*64 + kk)*11 + r] = acc;
        } else {
            int qq = q - 77;
            int sa = qq / 11, r = qq % 11;
            float acc = 0.f;
            for (int p = 0; p < 128; ++p)
                acc += wfrow[p] * jump_r[r*128 + p] * jl[sa*128 + p];
            if (brow) ws[OFF_BB + (t*20 + sa)*11 + r] = acc;
            else      ws[OFF_BT + ((t*64 + kk)*20 + sa)*11 + r] = acc;
        }
    }
}

// ---- K4: main scan --------------------------------------------------------
__launch_bounds__(256, 2)
__global__ void k_main(const float* __restrict__ W1, const float* __restrict__ b1,
                       const float* __restrict__ W2, const float* __restrict__ b2,
                       const float* __restrict__ Wf1, const float* __restrict__ bf1,
                       const float* __restrict__ Wf2, const float* __restrict__ bf2,
                       const int*   __restrict__ rt0, const float* __restrict__ xt0,
                       const float* __restrict__ yt0, const float* __restrict__ dBx,
                       const float* __restrict__ dBy, const float* __restrict__ junif,
                       const float* __restrict__ sunif, const float* __restrict__ jmg,
                       const float* __restrict__ cr,   const float* __restrict__ cfr,
                       const float* ws, float* wpart, float* out) {
    __shared__ float sjm[220], scr[11], scfr[11];
    int tid = threadIdx.x;
    for (int i = tid; i < 220; i += 256) sjm[i] = jmg[i];
    if (tid < 11) { scr[tid] = cr[tid]; scfr[tid] = cfr[tid]; }
    __syncthreads();

    int lane = tid & 63;
    int w = __builtin_amdgcn_readfirstlane(tid >> 6);   // uniform wave id 0..3
    int b = blockIdx.x;
    int pg = b >> 1;                  // particle group 0..127
    int jg = ((b & 1) << 2) | w;      // k-slice id 0..7 (uniform)
    int k0 = jg * 8;                  // my 8 hidden columns
    int gp = pg * 64 + lane;          // global particle
    bool desig = (jg == 0);

    int rt = rt0[gp];
    float xt[3], xin[3], yin[3], gtx[9], gty[9];
    #pragma unroll
    for (int i = 0; i < 3; ++i) { xt[i] = xt0[gp*3 + i]; xin[i] = xt[i]; yin[i] = yt0[gp*3 + i]; }
    #pragma unroll
    for (int i = 0; i < 9; ++i) { gtx[i] = (i % 4 == 0) ? 1.f : 0.f; gty[i] = gtx[i]; }
    float fun = 0.f, run = 1.f, upart = 0.f;

    for (int t = 0; t < NSTEP; ++t) {
        int base = t * BATCH + gp;
        float ju = junif[base], su = sunif[base];
        float dbx0 = dBx[base*2], dbx1 = dBx[base*2 + 1];
        float dby0 = dBy[base*3], dby1 = dBy[base*3 + 1], dby2 = dBy[base*3 + 2];
        int r = rt - 10;
        int jon = (ju < scr[r] * DT) ? 1 : 0;
        int cnt = 0;
        #pragma unroll
        for (int j = 0; j < 20; ++j) cnt += (su < sjm[r*20 + j]) ? 1 : 0;
        int ind = 20 - cnt;
        int drt = (ind < 10) ? (ind + 1) : -(ind - 9);
        drt = jon ? drt : 0;

        // T_inv without arccos/atan2
        float nx = fmaxf(sqrtf(xt[0]*xt[0] + xt[1]*xt[1] + xt[2]*xt[2]), 1e-12f);
        float c = fminf(1.f, fmaxf(-1.f, xt[2] / nx));
        float ct = sqrtf(fmaxf(0.f, 1.f - c*c));
        float st = -c;
        float rxy2 = xt[0]*xt[0] + xt[1]*xt[1];
        float cp = 1.f, sp = 0.f;
        if (rxy2 > 0.f) { float ir = 1.0f / sqrtf(rxy2); cp = xt[0]*ir; sp = xt[1]*ir; }
        float Ti[9];
        Ti[0] = cp*ct; Ti[1] = -sp; Ti[2] = cp*st;
        Ti[3] = sp*ct; Ti[4] = cp;  Ti[5] = sp*st;
        Ti[6] = -st;   Ti[7] = 0.f; Ti[8] = ct;

        float inp[6] = {xin[0], xin[1], xin[2], yin[0], yin[1], yin[2]};

        // h-net: L1 full (replicated), L2 slice of 8
        float h1[64];
        const float* W1t = W1 + t*384; const float* b1t = b1 + t*64;
        #pragma unroll
        for (int j = 0; j < 64; ++j) {
            float a = b1t[j];
            #pragma unroll
            for (int i = 0; i < 6; ++i) a = fmaf(inp[i], W1t[i*64 + j], a);
            h1[j] = tanh_f(a);
        }
        const float* W2t = W2 + t*4096; const float* b2t = b2 + t*64;
        float h2[8];
        #pragma unroll
        for (int jj = 0; jj < 8; ++jj) h2[jj] = b2t[k0 + jj];
        #pragma unroll
        for (int k = 0; k < 64; ++k) {
            float hv = h1[k];
            const float* wr = W2t + k*64 + k0;
            #pragma unroll
            for (int jj = 0; jj < 8; ++jj) h2[jj] = fmaf(hv, wr[jj], h2[jj]);
        }
        #pragma unroll
        for (int jj = 0; jj < 8; ++jj) h2[jj] = tanh_f(h2[jj]);

        // gu partial via W3e tables (gathered per-lane r)
        float gup[6] = {0.f, 0.f, 0.f, 0.f, 0.f, 0.f};
        #pragma unroll
        for (int jj = 0; jj < 8; ++jj) {
            const float* wp = ws + OFF_W3E + (size_t)((t*64 + k0 + jj)*6)*11 + r;
            float hv = h2[jj];
            #pragma unroll
            for (int o = 0; o < 6; ++o) gup[o] = fmaf(hv, wp[o*11], gup[o]);
        }
        if (desig) {
            const float* bp = ws + OFF_B3E + t*66 + r;
            #pragma unroll
            for (int o = 0; o < 6; ++o) gup[o] += bp[o*11];
        }

        // f-net (reuse h1)
        const float* Wf1t = Wf1 + t*384; const float* bf1t = bf1 + t*64;
        #pragma unroll
        for (int j = 0; j < 64; ++j) {
            float a = bf1t[j];
            #pragma unroll
            for (int i = 0; i < 6; ++i) a = fmaf(inp[i], Wf1t[i*64 + j], a);
            h1[j] = tanh_f(a);
        }
        const float* Wf2t = Wf2 + t*4096; const float* bf2t = bf2 + t*64;
        float hf2[8];
        #pragma unroll
        for (int jj = 0; jj < 8; ++jj) hf2[jj] = bf2t[k0 + jj];
        #pragma unroll
        for (int k = 0; k < 64; ++k) {
            float hv = h1[k];
            const float* wr = Wf2t + k*64 + k0;
            #pragma unroll
            for (int jj = 0; jj < 8; ++jj) hf2[jj] = fmaf(hv, wr[jj], hf2[jj]);
        }
        #pragma unroll
        for (int jj = 0; jj < 8; ++jj) hf2[jj] = tanh_f(hf2[jj]);

        // jump partial
        int sa = (drt > 0) ? (drt - 1) : ((drt < 0) ? (9 - drt) : 0);
        float hc = 0.f, hb = 0.f;
        #pragma unroll
        for (int jj = 0; jj < 8; ++jj) {
            int kidx = t*64 + k0 + jj;
            hc = fmaf(hf2[jj], ws[OFF_CT + (size_t)kidx*11 + r], hc);
            hb = fmaf(hf2[jj], ws[OFF_BT + ((size_t)kidx*20 + sa)*11 + r], hb);
        }
        float jflag = (drt != 0) ? 1.f : 0.f;
        float jpart = jflag*hb - DT*hc;
        if (desig)
            jpart += jflag*ws[OFF_BB + (t*20 + sa)*11 + r] - DT*ws[OFF_BC + t*11 + r];

        // diff partial: coefficients c_o from geometry (linear in gu)
        float sdx = 1.0f / (float)rt;   // sqrt(2*DXC) == 1
        float dpart = jpart;
        #pragma unroll
        for (int i = 0; i < 3; ++i) {
            float w30 = gtx[i*3]*Ti[0] + gtx[i*3+1]*Ti[3] + gtx[i*3+2]*Ti[6];
            (void)w30;
            float w31 = gtx[i*3]*Ti[1] + gtx[i*3+1]*Ti[4] + gtx[i*3+2]*Ti[7];
            float w32 = gtx[i*3]*Ti[2] + gtx[i*3+1]*Ti[5] + gtx[i*3+2]*Ti[8];
            float cx = sdx * (w31*dbx1 - w32*dbx0);
            float cy = gty[i*3]*dby0 + gty[i*3+1]*dby1 + gty[i*3+2]*dby2;
            dpart += gup[i]*cx + gup[3+i]*cy;
        }
        upart += run * __expf(-fun) * dpart;
        fun += scfr[r] * DT;

        // position updates
        float dX0 = sdx*dbx0, dX1 = sdx*dbx1;
        float s0 = __sinf(dX0), c0 = __cosf(dX0);
        float s1 = __sinf(dX1), c1 = __cosf(dX1);
        float cart0 = c0*c1 - 1.0f, cart1 = c0*s1, cart2 = -s0;
        float dX3[3];
        #pragma unroll
        for (int i = 0; i < 3; ++i)
            dX3[i] = Ti[i*3]*cart0 + Ti[i*3+1]*cart1 + Ti[i*3+2]*cart2;
        #pragma unroll
        for (int i = 0; i < 3; ++i) xt[i] += dX3[i];
        #pragma unroll
        for (int i = 0; i < 3; ++i)
            xin[i] += gtx[i*3]*dX3[0] + gtx[i*3+1]*dX3[1] + gtx[i*3+2]*dX3[2];
        #pragma unroll
        for (int i = 0; i < 3; ++i)
            yin[i] += gty[i*3]*dby0 + gty[i*3+1]*dby1 + gty[i*3+2]*dby2;
        rt += drt; rt = (rt < 10) ? 10 : ((rt > 20) ? 20 : rt);
        reflect3(xin, gtx);
        reflect3(yin, gty);
        float d0 = xin[0]-yin[0], d1 = xin[1]-yin[1], d2 = xin[2]-yin[2];
        if (sqrtf(d0*d0 + d1*d1 + d2*d2) < CAP_EPS) run = 0.f;
    }

    wpart[jg*BATCH + gp] = upart;
    if (desig) {
        float d0 = xin[0]-yin[0], d1 = xin[1]-yin[1], d2 = xin[2]-yin[2];
        float u0v = __expf(-(d0*d0 + d1*d1 + d2*d2));
        out[BATCH + gp] = run * u0v * __expf(-fun);
    }
}

// ---- K5: reduce partials --------------------------------------------------
__global__ void k_reduce(const float* wpart, const float* __restrict__ u, float* out) {
    int g = blockIdx.x * 256 + threadIdx.x;
    if (g < BATCH) {
        float a = u[0];
        #pragma unroll
        for (int jg = 0; jg < 8; ++jg) a += wpart[jg*BATCH + g];
        out[g] = a;
    }
}

extern "C" void kernel_launch(void* const* d_in, const int* in_sizes, int n_in,
                              void* d_out, int out_size, void* d_ws, size_t ws_size,
                              hipStream_t stream) {
    const float* u      = (const float*)d_in[0];
    const float* jump_r = (const float*)d_in[1];
    const float* jump_l = (const float*)d_in[2];
    const float* W1  = (const float*)d_in[3];
    const float* b1  = (const float*)d_in[4];
    const float* W2  = (const float*)d_in[5];
    const float* b2  = (const float*)d_in[6];
    const float* W3  = (const float*)d_in[7];
    const float* b3  = (const float*)d_in[8];
    const float* emb = (const float*)d_in[9];
    const float* Wf1 = (const float*)d_in[10];
    const float* bf1 = (const float*)d_in[11];
    const float* Wf2 = (const float*)d_in[12];
    const float* bf2 = (const float*)d_in[13];
    const float* Wf3 = (const float*)d_in[14];
    const float* bf3 = (const float*)d_in[15];
    const int*   rt0 = (const int*)d_in[16];
    const float* xt0 = (const float*)d_in[17];
    const float* yt0 = (const float*)d_in[18];
    const float* dBx = (const float*)d_in[19];
    const float* dBy = (const float*)d_in[20];
    const float* junif = (const float*)d_in[21];
    const float* sunif = (const float*)d_in[22];
    const float* mcu = (const float*)d_in[23];
    const float* jm  = (const float*)d_in[24];
    const float* cr  = (const float*)d_in[25];
    const float* cfr = (const float*)d_in[26];
    float* ws  = (float*)d_ws;
    float* out = (float*)d_out;

    hipMemsetAsync(ws + OFF_HIST, 0, 220*sizeof(int), stream);
    k_hist<<<430, 256, 0, stream>>>(mcu, jm, (int*)(ws + OFF_HIST));
    k_mcj<<<6, 256, 0, stream>>>((const int*)(ws + OFF_HIST), jump_l, cr, ws + OFF_MCJ);
    k_tables<<<64*65, 256, 0, stream>>>(W3, b3, emb, Wf3, bf3, jump_r, jump_l,
                                        ws + OFF_MCJ, ws);
    k_main<<<256, 256, 0, stream>>>(W1, b1, W2, b2, Wf1, bf1, Wf2, bf2,
                                    rt0, xt0, yt0, dBx, dBy, junif, sunif,
                                    jm, cr, cfr, ws, ws + OFF_PART, out);
    k_reduce<<<32, 256, 0, stream>>>(ws + OFF_PART, u, out);
}

// Round 2
// 1019.677 us; speedup vs baseline: 1.9977x; 1.9977x over previous
//
#include <hip/hip_runtime.h>
#include <math.h>

#define NUMR 11
#define NSTEP 64
#define BATCH 8192
#define PDIM 128
#define MC 10000
#define DT (1.0f/64.0f)
#define RDOM 5.0f
#define CAP_EPS 0.1f

// workspace float offsets
#define OFF_HIST 0              // 220 ints
#define OFF_MCJ  256            // 11*128 = 1408
#define OFF_W3E  1664           // [t][r][k*6+o] 64*11*384 = 270336
#define OFF_B3E  272000         // [t][r][o]     64*11*6   = 4224
#define OFF_BT   276224         // [t][r][sa][k] 64*11*20*64 = 901120
#define OFF_BB   1177344        // [t][r][sa]    64*11*20  = 14080
#define OFF_CT   1191424        // [t][r][k]     64*11*64  = 45056
#define OFF_BC   1236480        // [t][r]        704
#define OFF_PART 1237184        // 16*8192 = 131072
#define OFF_META 1368256        // ushort[64][8192] = 262144 floats
#define OFF_EFUN 1630400        // float[64][8192] = 524288
#define OFF_EFUNF 2154688       // float[8192]
// end: 2162880 floats (~8.7 MB)

__device__ __forceinline__ float tanh_f(float x) {
    float e = __expf(2.0f * x);
    return 1.0f - 2.0f * __builtin_amdgcn_rcpf(e + 1.0f);
}

__device__ __forceinline__ void reflect3(float* p, float* g) {
    float nr = sqrtf(p[0]*p[0] + p[1]*p[1] + p[2]*p[2]);
    if (nr > RDOM) {
        float inv = 1.0f / fmaxf(nr, 1e-12f);   // exact div: trajectory-sensitive
        float nb0 = p[0]*inv, nb1 = p[1]*inv, nb2 = p[2]*inv;
        float sc = 2.0f*RDOM - nr;
        p[0] = nb0*sc; p[1] = nb1*sc; p[2] = nb2*sc;
        #pragma unroll
        for (int j = 0; j < 3; ++j) {
            float proj = nb0*g[j] + nb1*g[3+j] + nb2*g[6+j];
            g[j]   -= 2.0f*nb0*proj;
            g[3+j] -= 2.0f*nb1*proj;
            g[6+j] -= 2.0f*nb2*proj;
        }
    }
}

// ---- K0: per-particle r-path precompute ----------------------------------
__global__ void k_path(const int* __restrict__ rt0, const float* __restrict__ junif,
                       const float* __restrict__ sunif, const float* __restrict__ jm,
                       const float* __restrict__ cr, const float* __restrict__ cfr,
                       unsigned short* meta, float* efun, float* efunF) {
    int p = blockIdx.x * 256 + threadIdx.x;
    if (p >= BATCH) return;
    int rt = rt0[p];
    float fun = 0.f;
    for (int t = 0; t < NSTEP; ++t) {
        int r = rt - 10;
        float ju = junif[t*BATCH + p], su = sunif[t*BATCH + p];
        int jon = (ju < cr[r] * DT) ? 1 : 0;
        int cnt = 0;
        #pragma unroll
        for (int j = 0; j < 20; ++j) cnt += (su < jm[r*20 + j]) ? 1 : 0;
        int ind = 20 - cnt;
        int drt = (ind < 10) ? (ind + 1) : -(ind - 9);
        drt = jon ? drt : 0;
        int code = (drt > 0) ? drt : ((drt < 0) ? (10 - drt) : 0);  // 0=no jump, 1..10 pos, 11..20 neg
        meta[t*BATCH + p] = (unsigned short)(r | (code << 8));
        efun[t*BATCH + p] = __expf(-fun);
        fun += cfr[r] * DT;
        rt += drt; rt = (rt < 10) ? 10 : ((rt > 20) ? 20 : rt);
    }
    efunF[p] = __expf(-fun);
}

// ---- K1: histogram of MC jump sizes per (r, sa) --------------------------
__global__ void k_hist(const float* __restrict__ mcu, const float* __restrict__ jm,
                       int* hist) {
    __shared__ int lh[220];
    int tid = threadIdx.x;
    for (int i = tid; i < 220; i += 256) lh[i] = 0;
    __syncthreads();
    int i = blockIdx.x * 256 + tid;
    if (i < MC * NUMR) {
        int r = i % NUMR;
        float u = mcu[i];
        int cnt = 0;
        #pragma unroll
        for (int j = 0; j < 20; ++j) cnt += (u < jm[r*20 + j]) ? 1 : 0;
        int ind = 20 - cnt;
        int s = (ind < 10) ? (ind + 1) : -(ind - 9);
        int sa = (s > 0) ? (s - 1) : (10 + (-s - 1));
        atomicAdd(&lh[r*20 + sa], 1);
    }
    __syncthreads();
    for (int q = tid; q < 220; q += 256) if (lh[q]) atomicAdd(&hist[q], lh[q]);
}

// ---- K2: mc_jump[r][p] ----------------------------------------------------
__global__ void k_mcj(const int* hist, const float* __restrict__ jl,
                      const float* __restrict__ cr, float* mcj) {
    int i = blockIdx.x * 256 + threadIdx.x;
    if (i >= NUMR * PDIM) return;
    int r = i / PDIM, p = i % PDIM;
    float acc = 0.f;
    #pragma unroll
    for (int sa = 0; sa < 20; ++sa)
        acc += (float)hist[r*20 + sa] * jl[sa*PDIM + p];
    mcj[r*PDIM + p] = acc * cr[r] * (1.0f / (float)MC);
}

// ---- K3: per-step contraction tables (r-fast → float4-gatherable) --------
__global__ void k_tables(const float* __restrict__ W3, const float* __restrict__ b3,
                         const float* __restrict__ emb, const float* __restrict__ Wf3,
                         const float* __restrict__ bf3, const float* __restrict__ jump_r,
                         const float* __restrict__ jl, const float* __restrict__ mcj,
                         float* ws) {
    int t  = blockIdx.x / 65;
    int kk = blockIdx.x % 65;
    bool brow = (kk == 64);
    const float* w3row = brow ? (b3 + t*768) : (W3 + (t*64 + kk)*768);
    const float* wfrow = brow ? (bf3 + t*128) : (Wf3 + (t*64 + kk)*128);
    for (int q = threadIdx.x; q < 297; q += blockDim.x) {
        if (q < 66) {
            int o = q / 11, r = q % 11;
            const float* e = emb + (t*11 + r)*128;
            float acc = 0.f;
            for (int p = 0; p < 128; ++p) acc += e[p] * w3row[p*6 + o];
            if (brow) ws[OFF_B3E + (t*11 + r)*6 + o] = acc;
            else      ws[OFF_W3E + (size_t)(t*11 + r)*384 + kk*6 + o] = acc;
        } else if (q < 77) {
            int r = q - 66;
            float acc = 0.f;
            for (int p = 0; p < 128; ++p)
                acc += wfrow[p] * jump_r[r*128 + p] * mcj[r*128 + p];
            if (brow) ws[OFF_BC + t*11 + r] = acc;
            else      ws[OFF_CT + (t*11 + r)*64 + kk] = acc;
        } else {
            int qq = q - 77;
            int sa = qq / 11, r = qq % 11;
            float acc = 0.f;
            for (int p = 0; p < 128; ++p)
                acc += wfrow[p] * jump_r[r*128 + p] * jl[sa*128 + p];
            if (brow) ws[OFF_BB + (t*11 + r)*20 + sa] = acc;
            else      ws[OFF_BT + ((size_t)(t*11 + r)*20 + sa)*64 + kk] = acc;
        }
    }
}

// ---- K4: main scan. block = 4 waves sharing one particle group; L1 in LDS.
__launch_bounds__(256, 2)
__global__ void k_main(const float* __restrict__ W1, const float* __restrict__ b1,
                       const float* __restrict__ W2, const float* __restrict__ b2,
                       const float* __restrict__ Wf1, const float* __restrict__ bf1,
                       const float* __restrict__ Wf2, const float* __restrict__ bf2,
                       const float* __restrict__ xt0, const float* __restrict__ yt0,
                       const float* __restrict__ dBx, const float* __restrict__ dBy,
                       const unsigned short* __restrict__ meta,
                       const float* __restrict__ efun, const float* __restrict__ efunF,
                       const float* __restrict__ ws, float* wpart, float* out) {
    __shared__ float h1s[64][65];
    __shared__ float f1s[64][65];
    int tid = threadIdx.x;
    int lane = tid & 63;
    int w = __builtin_amdgcn_readfirstlane(tid >> 6);  // wave 0..3 (uniform)
    int blk = blockIdx.x;
    int pg = blk >> 2, q = blk & 3;
    int jg = q*4 + w;          // global k-slice 0..15
    int c0 = jg*4;             // my 4 L2 columns
    int j0 = w*16;             // my 16 L1 rows
    int gp = pg*64 + lane;
    bool desig = (jg == 0);

    float xt[3], xin[3], yin[3], gtx[9], gty[9];
    #pragma unroll
    for (int i = 0; i < 3; ++i) { xt[i] = xt0[gp*3 + i]; xin[i] = xt[i]; yin[i] = yt0[gp*3 + i]; }
    #pragma unroll
    for (int i = 0; i < 9; ++i) { gtx[i] = (i % 4 == 0) ? 1.f : 0.f; gty[i] = gtx[i]; }
    float run = 1.f, upart = 0.f;

    #pragma unroll 1
    for (int t = 0; t < NSTEP; ++t) {
        int base = t * BATCH + gp;
        unsigned short mv = meta[base];
        int r = mv & 0xff;
        int code = mv >> 8;
        float jflag = (code != 0) ? 1.f : 0.f;
        int sa = (code > 0) ? (code - 1) : 0;
        float ef = efun[base];
        float dbx0 = dBx[base*2], dbx1 = dBx[base*2 + 1];
        const float* pby = dBy + (size_t)base*3;
        float dby0 = pby[0], dby1 = pby[1], dby2 = pby[2];

        // T_inv without arccos/atan2
        float nx = fmaxf(sqrtf(xt[0]*xt[0] + xt[1]*xt[1] + xt[2]*xt[2]), 1e-12f);
        float c = fminf(1.f, fmaxf(-1.f, xt[2] / nx));
        float ct = sqrtf(fmaxf(0.f, 1.f - c*c));
        float st = -c;
        float rxy2 = xt[0]*xt[0] + xt[1]*xt[1];
        float cp = 1.f, sp = 0.f;
        if (rxy2 > 0.f) { float ir = 1.0f / sqrtf(rxy2); cp = xt[0]*ir; sp = xt[1]*ir; }
        float Ti[9];
        Ti[0] = cp*ct; Ti[1] = -sp; Ti[2] = cp*st;
        Ti[3] = sp*ct; Ti[4] = cp;  Ti[5] = sp*st;
        Ti[6] = -st;   Ti[7] = 0.f; Ti[8] = ct;

        float inp[6] = {xin[0], xin[1], xin[2], yin[0], yin[1], yin[2]};

        // L1 slice (both nets) -> LDS
        const float* W1t  = W1  + t*384 + j0;
        const float* Wf1t = Wf1 + t*384 + j0;
        const float* b1t  = b1  + t*64 + j0;
        const float* bf1t = bf1 + t*64 + j0;
        #pragma unroll
        for (int j = 0; j < 16; ++j) {
            float a  = b1t[j];
            float af = bf1t[j];
            #pragma unroll
            for (int i = 0; i < 6; ++i) {
                a  = fmaf(inp[i], W1t[i*64 + j], a);
                af = fmaf(inp[i], Wf1t[i*64 + j], af);
            }
            h1s[lane][j0 + j] = tanh_f(a);
            f1s[lane][j0 + j] = tanh_f(af);
        }
        __syncthreads();

        // L2: my 4 columns, both nets
        const float* W2t  = W2  + t*4096 + c0;
        const float* Wf2t = Wf2 + t*4096 + c0;
        float acc[4], fac[4];
        #pragma unroll
        for (int cc = 0; cc < 4; ++cc) {
            acc[cc] = b2[t*64 + c0 + cc];
            fac[cc] = bf2[t*64 + c0 + cc];
        }
        #pragma unroll 8
        for (int k = 0; k < 64; ++k) {
            float hv = h1s[lane][k];
            float fv = f1s[lane][k];
            #pragma unroll
            for (int cc = 0; cc < 4; ++cc) {
                acc[cc] = fmaf(hv, W2t[k*64 + cc], acc[cc]);
                fac[cc] = fmaf(fv, Wf2t[k*64 + cc], fac[cc]);
            }
        }
        __syncthreads();   // all LDS reads for step t done

        float h2[4], hf2[4];
        #pragma unroll
        for (int cc = 0; cc < 4; ++cc) { h2[cc] = tanh_f(acc[cc]); hf2[cc] = tanh_f(fac[cc]); }

        // gu partial via W3E (6 aligned float4 per lane)
        const float4* w3p = (const float4*)(ws + OFF_W3E + (size_t)(t*11 + r)*384 + c0*6);
        float wv[24];
        #pragma unroll
        for (int i = 0; i < 6; ++i) {
            float4 v = w3p[i];
            wv[i*4+0] = v.x; wv[i*4+1] = v.y; wv[i*4+2] = v.z; wv[i*4+3] = v.w;
        }
        float gup[6] = {0.f, 0.f, 0.f, 0.f, 0.f, 0.f};
        #pragma unroll
        for (int cc = 0; cc < 4; ++cc)
            #pragma unroll
            for (int o = 0; o < 6; ++o)
                gup[o] = fmaf(h2[cc], wv[cc*6 + o], gup[o]);
        if (desig) {
            const float* bp = ws + OFF_B3E + (t*11 + r)*6;
            #pragma unroll
            for (int o = 0; o < 6; ++o) gup[o] += bp[o];
        }

        // jump partial (1 float4 each from CT/BT)
        float4 ctv = *(const float4*)(ws + OFF_CT + (size_t)(t*11 + r)*64 + c0);
        float4 btv = *(const float4*)(ws + OFF_BT + ((size_t)(t*11 + r)*20 + sa)*64 + c0);
        float hc = hf2[0]*ctv.x + hf2[1]*ctv.y + hf2[2]*ctv.z + hf2[3]*ctv.w;
        float hb = hf2[0]*btv.x + hf2[1]*btv.y + hf2[2]*btv.z + hf2[3]*btv.w;
        float jpart = jflag*hb - DT*hc;
        if (desig)
            jpart += jflag*ws[OFF_BB + (t*11 + r)*20 + sa] - DT*ws[OFF_BC + t*11 + r];

        // diff partial
        float sdx = 1.0f / (float)(r + 10);
        float dpart = jpart;
        #pragma unroll
        for (int i = 0; i < 3; ++i) {
            float w31 = gtx[i*3]*Ti[1] + gtx[i*3+1]*Ti[4] + gtx[i*3+2]*Ti[7];
            float w32 = gtx[i*3]*Ti[2] + gtx[i*3+1]*Ti[5] + gtx[i*3+2]*Ti[8];
            float cx = sdx * (w31*dbx1 - w32*dbx0);
            float cy = gty[i*3]*dby0 + gty[i*3+1]*dby1 + gty[i*3+2]*dby2;
            dpart += gup[i]*cx + gup[3+i]*cy;
        }
        upart += run * ef * dpart;

        // position updates
        float dX0 = sdx*dbx0, dX1 = sdx*dbx1;
        float s0 = __sinf(dX0), cc0 = __cosf(dX0);
        float s1 = __sinf(dX1), cc1 = __cosf(dX1);
        float cart0 = cc0*cc1 - 1.0f, cart1 = cc0*s1, cart2 = -s0;
        float dX3[3];
        #pragma unroll
        for (int i = 0; i < 3; ++i)
            dX3[i] = Ti[i*3]*cart0 + Ti[i*3+1]*cart1 + Ti[i*3+2]*cart2;
        #pragma unroll
        for (int i = 0; i < 3; ++i) xt[i] += dX3[i];
        #pragma unroll
        for (int i = 0; i < 3; ++i)
            xin[i] += gtx[i*3]*dX3[0] + gtx[i*3+1]*dX3[1] + gtx[i*3+2]*dX3[2];
        #pragma unroll
        for (int i = 0; i < 3; ++i)
            yin[i] += gty[i*3]*dby0 + gty[i*3+1]*dby1 + gty[i*3+2]*dby2;
        reflect3(xin, gtx);
        reflect3(yin, gty);
        float d0 = xin[0]-yin[0], d1 = xin[1]-yin[1], d2 = xin[2]-yin[2];
        if (sqrtf(d0*d0 + d1*d1 + d2*d2) < CAP_EPS) run = 0.f;
    }

    wpart[jg*BATCH + gp] = upart;
    if (desig) {
        float d0 = xin[0]-yin[0], d1 = xin[1]-yin[1], d2 = xin[2]-yin[2];
        float u0v = __expf(-(d0*d0 + d1*d1 + d2*d2));
        out[BATCH + gp] = run * u0v * efunF[gp];
    }
}

// ---- K5: reduce partials --------------------------------------------------
__global__ void k_reduce(const float* wpart, const float* __restrict__ u, float* out) {
    int g = blockIdx.x * 256 + threadIdx.x;
    if (g < BATCH) {
        float a = u[0];
        #pragma unroll
        for (int jg = 0; jg < 16; ++jg) a += wpart[jg*BATCH + g];
        out[g] = a;
    }
}

extern "C" void kernel_launch(void* const* d_in, const int* in_sizes, int n_in,
                              void* d_out, int out_size, void* d_ws, size_t ws_size,
                              hipStream_t stream) {
    const float* u      = (const float*)d_in[0];
    const float* jump_r = (const float*)d_in[1];
    const float* jump_l = (const float*)d_in[2];
    const float* W1  = (const float*)d_in[3];
    const float* b1  = (const float*)d_in[4];
    const float* W2  = (const float*)d_in[5];
    const float* b2  = (const float*)d_in[6];
    const float* W3  = (const float*)d_in[7];
    const float* b3  = (const float*)d_in[8];
    const float* emb = (const float*)d_in[9];
    const float* Wf1 = (const float*)d_in[10];
    const float* bf1 = (const float*)d_in[11];
    const float* Wf2 = (const float*)d_in[12];
    const float* bf2 = (const float*)d_in[13];
    const float* Wf3 = (const float*)d_in[14];
    const float* bf3 = (const float*)d_in[15];
    const int*   rt0 = (const int*)d_in[16];
    const float* xt0 = (const float*)d_in[17];
    const float* yt0 = (const float*)d_in[18];
    const float* dBx = (const float*)d_in[19];
    const float* dBy = (const float*)d_in[20];
    const float* junif = (const float*)d_in[21];
    const float* sunif = (const float*)d_in[22];
    const float* mcu = (const float*)d_in[23];
    const float* jm  = (const float*)d_in[24];
    const float* cr  = (const float*)d_in[25];
    const float* cfr = (const float*)d_in[26];
    float* ws  = (float*)d_ws;
    float* out = (float*)d_out;

    hipMemsetAsync(ws + OFF_HIST, 0, 220*sizeof(int), stream);
    k_path<<<32, 256, 0, stream>>>(rt0, junif, sunif, jm, cr, cfr,
                                   (unsigned short*)(ws + OFF_META),
                                   ws + OFF_EFUN, ws + OFF_EFUNF);
    k_hist<<<430, 256, 0, stream>>>(mcu, jm, (int*)(ws + OFF_HIST));
    k_mcj<<<6, 256, 0, stream>>>((const int*)(ws + OFF_HIST), jump_l, cr, ws + OFF_MCJ);
    k_tables<<<64*65, 256, 0, stream>>>(W3, b3, emb, Wf3, bf3, jump_r, jump_l,
                                        ws + OFF_MCJ, ws);
    k_main<<<512, 256, 0, stream>>>(W1, b1, W2, b2, Wf1, bf1, Wf2, bf2,
                                    xt0, yt0, dBx, dBy,
                                    (const unsigned short*)(ws + OFF_META),
                                    ws + OFF_EFUN, ws + OFF_EFUNF,
                                    ws, ws + OFF_PART, out);
    k_reduce<<<32, 256, 0, stream>>>(ws + OFF_PART, u, out);
}

// Round 3
// 619.929 us; speedup vs baseline: 3.2859x; 1.6448x over previous
//
#include <hip/hip_runtime.h>
#include <math.h>

#define NUMR 11
#define NSTEP 64
#define BATCH 8192
#define PDIM 128
#define MC 10000
#define DT (1.0f/64.0f)
#define RDOM 5.0f
#define CAP_EPS 0.1f
#define TP (NSTEP*BATCH)        // 524288

// workspace float offsets (total 9782848 floats = ~39.1 MB)
#define OFF_HIST 0              // 220 ints
#define OFF_MCJ  256            // 11*128 = 1408
#define OFF_W3E  1664           // [t][r][k*8+o(6 used)] 64*11*512 = 360448
#define OFF_B3E  362112         // [t][r][8]             64*11*8   = 5632
#define OFF_BT   367744         // [t][r][sa][k]         64*11*20*64 = 901120
#define OFF_BB   1268864        // [t][r][sa]            14080
#define OFF_CT   1282944        // [t][r][k]             45056
#define OFF_BC   1328000        // [t][r]                704
#define OFF_GEO  1328704        // 14 fields x [t][p] = 14*524288 = 7340032
#define OFF_CONTRIB 8668736     // [t][p] 524288
#define OFF_W2T  9193024        // [t][c][k] 262144
#define OFF_WF2T 9455168        // 262144
#define OFF_W1T  9717312        // [t][j][8] = {W1[0..5][j], b1[j], 0} 32768
#define OFF_WF1T 9750080        // 32768

__device__ __forceinline__ float tanh_f(float x) {
    float e = __expf(2.0f * x);
    return 1.0f - 2.0f * __builtin_amdgcn_rcpf(e + 1.0f);
}

__device__ __forceinline__ void reflect3(float* p, float* g) {
    float nr = sqrtf(p[0]*p[0] + p[1]*p[1] + p[2]*p[2]);
    if (nr > RDOM) {
        float inv = 1.0f / fmaxf(nr, 1e-12f);
        float nb0 = p[0]*inv, nb1 = p[1]*inv, nb2 = p[2]*inv;
        float sc = 2.0f*RDOM - nr;
        p[0] = nb0*sc; p[1] = nb1*sc; p[2] = nb2*sc;
        #pragma unroll
        for (int j = 0; j < 3; ++j) {
            float proj = nb0*g[j] + nb1*g[3+j] + nb2*g[6+j];
            g[j]   -= 2.0f*nb0*proj;
            g[3+j] -= 2.0f*nb1*proj;
            g[6+j] -= 2.0f*nb2*proj;
        }
    }
}

// ---- K1: histogram of MC jump sizes per (r, sa) --------------------------
__global__ void k_hist(const float* __restrict__ mcu, const float* __restrict__ jm,
                       int* hist) {
    __shared__ int lh[220];
    int tid = threadIdx.x;
    for (int i = tid; i < 220; i += 256) lh[i] = 0;
    __syncthreads();
    int i = blockIdx.x * 256 + tid;
    if (i < MC * NUMR) {
        int r = i % NUMR;
        float u = mcu[i];
        int cnt = 0;
        #pragma unroll
        for (int j = 0; j < 20; ++j) cnt += (u < jm[r*20 + j]) ? 1 : 0;
        int ind = 20 - cnt;
        int s = (ind < 10) ? (ind + 1) : -(ind - 9);
        int sa = (s > 0) ? (s - 1) : (10 + (-s - 1));
        atomicAdd(&lh[r*20 + sa], 1);
    }
    __syncthreads();
    for (int q = tid; q < 220; q += 256) if (lh[q]) atomicAdd(&hist[q], lh[q]);
}

// ---- K2: mc_jump[r][p] ----------------------------------------------------
__global__ void k_mcj(const int* hist, const float* __restrict__ jl,
                      const float* __restrict__ cr, float* mcj) {
    int i = blockIdx.x * 256 + threadIdx.x;
    if (i >= NUMR * PDIM) return;
    int r = i / PDIM, p = i % PDIM;
    float acc = 0.f;
    #pragma unroll
    for (int sa = 0; sa < 20; ++sa)
        acc += (float)hist[r*20 + sa] * jl[sa*PDIM + p];
    mcj[r*PDIM + p] = acc * cr[r] * (1.0f / (float)MC);
}

// ---- K3: per-step contraction tables -------------------------------------
__global__ void k_tables(const float* __restrict__ W3, const float* __restrict__ b3,
                         const float* __restrict__ emb, const float* __restrict__ Wf3,
                         const float* __restrict__ bf3, const float* __restrict__ jump_r,
                         const float* __restrict__ jl, const float* __restrict__ mcj,
                         float* ws) {
    int t  = blockIdx.x / 65;
    int kk = blockIdx.x % 65;
    bool brow = (kk == 64);
    const float* w3row = brow ? (b3 + t*768) : (W3 + (t*64 + kk)*768);
    const float* wfrow = brow ? (bf3 + t*128) : (Wf3 + (t*64 + kk)*128);
    for (int q = threadIdx.x; q < 297; q += blockDim.x) {
        if (q < 66) {
            int o = q / 11, r = q % 11;
            const float* e = emb + (t*11 + r)*128;
            float a0 = 0.f, a1 = 0.f;
            #pragma unroll 4
            for (int p = 0; p < 128; p += 2) {
                a0 = fmaf(e[p],   w3row[p*6 + o],     a0);
                a1 = fmaf(e[p+1], w3row[(p+1)*6 + o], a1);
            }
            float acc = a0 + a1;
            if (brow) ws[OFF_B3E + (t*11 + r)*8 + o] = acc;
            else      ws[OFF_W3E + (size_t)((t*11 + r)*64 + kk)*8 + o] = acc;
        } else if (q < 77) {
            int r = q - 66;
            float a0 = 0.f, a1 = 0.f;
            #pragma unroll 4
            for (int p = 0; p < 128; p += 2) {
                a0 = fmaf(wfrow[p],   jump_r[r*128 + p]   * mcj[r*128 + p],   a0);
                a1 = fmaf(wfrow[p+1], jump_r[r*128 + p+1] * mcj[r*128 + p+1], a1);
            }
            float acc = a0 + a1;
            if (brow) ws[OFF_BC + t*11 + r] = acc;
            else      ws[OFF_CT + (t*11 + r)*64 + kk] = acc;
        } else {
            int qq = q - 77;
            int sa = qq / 11, r = qq % 11;
            float a0 = 0.f, a1 = 0.f;
            #pragma unroll 4
            for (int p = 0; p < 128; p += 2) {
                a0 = fmaf(wfrow[p],   jump_r[r*128 + p]   * jl[sa*128 + p],   a0);
                a1 = fmaf(wfrow[p+1], jump_r[r*128 + p+1] * jl[sa*128 + p+1], a1);
            }
            float acc = a0 + a1;
            if (brow) ws[OFF_BB + (t*11 + r)*20 + sa] = acc;
            else      ws[OFF_BT + ((size_t)(t*11 + r)*20 + sa)*64 + kk] = acc;
        }
    }
}

// ---- K3b: weight transposes ----------------------------------------------
__global__ void k_wt(const float* __restrict__ W1, const float* __restrict__ b1,
                     const float* __restrict__ Wf1, const float* __restrict__ bf1,
                     const float* __restrict__ W2, const float* __restrict__ Wf2,
                     float* ws) {
    int t = blockIdx.x, tid = threadIdx.x;
    for (int i = tid; i < 4096; i += 256) {
        int k = i >> 6, c = i & 63;
        ws[OFF_W2T  + t*4096 + c*64 + k] = W2[t*4096 + k*64 + c];
        ws[OFF_WF2T + t*4096 + c*64 + k] = Wf2[t*4096 + k*64 + c];
    }
    for (int i = tid; i < 512; i += 256) {
        int j = i >> 3, o = i & 7;
        float v  = (o < 6) ? W1[t*384 + o*64 + j]  : ((o == 6) ? b1[t*64 + j]  : 0.f);
        float vf = (o < 6) ? Wf1[t*384 + o*64 + j] : ((o == 6) ? bf1[t*64 + j] : 0.f);
        ws[OFF_W1T  + t*512 + i] = v;
        ws[OFF_WF1T + t*512 + i] = vf;
    }
}

// ---- K4: trajectory (sequential part only) -------------------------------
__launch_bounds__(256)
__global__ void k_geom(const int* __restrict__ rt0, const float* __restrict__ xt0,
                       const float* __restrict__ yt0, const float* __restrict__ dBx,
                       const float* __restrict__ dBy, const float* __restrict__ junif,
                       const float* __restrict__ sunif, const float* __restrict__ jm,
                       const float* __restrict__ cr, const float* __restrict__ cfr,
                       float* GEO, float* out) {
    __shared__ float sjm[220], scr[11], scfr[11];
    int tid = threadIdx.x;
    for (int i = tid; i < 220; i += 256) sjm[i] = jm[i];
    if (tid < 11) { scr[tid] = cr[tid]; scfr[tid] = cfr[tid]; }
    __syncthreads();
    int p = blockIdx.x * 256 + tid;

    int rt = rt0[p];
    float xt[3], xin[3], yin[3], gtx[9], gty[9];
    #pragma unroll
    for (int i = 0; i < 3; ++i) { xt[i] = xt0[p*3 + i]; xin[i] = xt[i]; yin[i] = yt0[p*3 + i]; }
    #pragma unroll
    for (int i = 0; i < 9; ++i) { gtx[i] = (i % 4 == 0) ? 1.f : 0.f; gty[i] = gtx[i]; }
    float fun = 0.f, run = 1.f;

    // prefetch step 0
    float ju = junif[p], su = sunif[p];
    float dbx0 = dBx[(size_t)p*2], dbx1 = dBx[(size_t)p*2 + 1];
    float dby0 = dBy[(size_t)p*3], dby1 = dBy[(size_t)p*3 + 1], dby2 = dBy[(size_t)p*3 + 2];

    int* GEOi = (int*)GEO;
    #pragma unroll 1
    for (int t = 0; t < NSTEP; ++t) {
        // issue next-step loads early (latency hidden behind this step's math)
        float nju = 0.f, nsu = 0.f, ndbx0 = 0.f, ndbx1 = 0.f, ndby0 = 0.f, ndby1 = 0.f, ndby2 = 0.f;
        if (t < NSTEP - 1) {
            int nb = (t + 1) * BATCH + p;
            nju = junif[nb]; nsu = sunif[nb];
            ndbx0 = dBx[(size_t)nb*2]; ndbx1 = dBx[(size_t)nb*2 + 1];
            ndby0 = dBy[(size_t)nb*3]; ndby1 = dBy[(size_t)nb*3 + 1]; ndby2 = dBy[(size_t)nb*3 + 2];
        }
        int base = t * BATCH + p;
        int r = rt - 10;
        int jon = (ju < scr[r] * DT) ? 1 : 0;
        int cnt = 0;
        #pragma unroll
        for (int j = 0; j < 20; ++j) cnt += (su < sjm[r*20 + j]) ? 1 : 0;
        int ind = 20 - cnt;
        int drt = (ind < 10) ? (ind + 1) : -(ind - 9);
        drt = jon ? drt : 0;
        int sa = (drt > 0) ? (drt - 1) : ((drt < 0) ? (9 - drt) : 0);
        int jf = (drt != 0) ? 1 : 0;

        // T_inv
        float nx = fmaxf(sqrtf(xt[0]*xt[0] + xt[1]*xt[1] + xt[2]*xt[2]), 1e-12f);
        float c = fminf(1.f, fmaxf(-1.f, xt[2] / nx));
        float ct = sqrtf(fmaxf(0.f, 1.f - c*c));
        float st = -c;
        float rxy2 = xt[0]*xt[0] + xt[1]*xt[1];
        float cp = 1.f, sp = 0.f;
        if (rxy2 > 0.f) { float ir = 1.0f / sqrtf(rxy2); cp = xt[0]*ir; sp = xt[1]*ir; }
        float Ti[9];
        Ti[0] = cp*ct; Ti[1] = -sp; Ti[2] = cp*st;
        Ti[3] = sp*ct; Ti[4] = cp;  Ti[5] = sp*st;
        Ti[6] = -st;   Ti[7] = 0.f; Ti[8] = ct;

        float sdx = 1.0f / (float)(r + 10);
        float scale = run * __expf(-fun);

        // store MLP inputs + linear coefficients
        #pragma unroll
        for (int i = 0; i < 3; ++i) {
            GEO[i*TP + base]       = xin[i];
            GEO[(3 + i)*TP + base] = yin[i];
        }
        #pragma unroll
        for (int i = 0; i < 3; ++i) {
            float w31 = gtx[i*3]*Ti[1] + gtx[i*3+1]*Ti[4] + gtx[i*3+2]*Ti[7];
            float w32 = gtx[i*3]*Ti[2] + gtx[i*3+1]*Ti[5] + gtx[i*3+2]*Ti[8];
            GEO[(6 + i)*TP + base] = sdx * (w31*dbx1 - w32*dbx0);
            GEO[(9 + i)*TP + base] = gty[i*3]*dby0 + gty[i*3+1]*dby1 + gty[i*3+2]*dby2;
        }
        GEO[12*TP + base]  = scale;
        GEOi[13*TP + base] = r | (sa << 8) | (jf << 16);

        fun += scfr[r] * DT;

        // position updates
        float dX0 = sdx*dbx0, dX1 = sdx*dbx1;
        float s0 = __sinf(dX0), cc0 = __cosf(dX0);
        float s1 = __sinf(dX1), cc1 = __cosf(dX1);
        float cart0 = cc0*cc1 - 1.0f, cart1 = cc0*s1, cart2 = -s0;
        float dX3[3];
        #pragma unroll
        for (int i = 0; i < 3; ++i)
            dX3[i] = Ti[i*3]*cart0 + Ti[i*3+1]*cart1 + Ti[i*3+2]*cart2;
        #pragma unroll
        for (int i = 0; i < 3; ++i) xt[i] += dX3[i];
        #pragma unroll
        for (int i = 0; i < 3; ++i)
            xin[i] += gtx[i*3]*dX3[0] + gtx[i*3+1]*dX3[1] + gtx[i*3+2]*dX3[2];
        #pragma unroll
        for (int i = 0; i < 3; ++i)
            yin[i] += gty[i*3]*dby0 + gty[i*3+1]*dby1 + gty[i*3+2]*dby2;
        rt += drt; rt = (rt < 10) ? 10 : ((rt > 20) ? 20 : rt);
        reflect3(xin, gtx);
        reflect3(yin, gty);
        float d0 = xin[0]-yin[0], d1 = xin[1]-yin[1], d2 = xin[2]-yin[2];
        if (sqrtf(d0*d0 + d1*d1 + d2*d2) < CAP_EPS) run = 0.f;

        ju = nju; su = nsu; dbx0 = ndbx0; dbx1 = ndbx1;
        dby0 = ndby0; dby1 = ndby1; dby2 = ndby2;
    }
    float d0 = xin[0]-yin[0], d1 = xin[1]-yin[1], d2 = xin[2]-yin[2];
    float u0v = __expf(-(d0*d0 + d1*d1 + d2*d2));
    out[BATCH + p] = run * u0v * __expf(-fun);
}

// ---- K5: batched MLP over all (t, particle) -------------------------------
__launch_bounds__(256, 3)
__global__ void k_mlp(const float* __restrict__ ws, const float* __restrict__ b2,
                      const float* __restrict__ bf2,
                      const float* __restrict__ GEO, float* __restrict__ contrib) {
    int t = blockIdx.x >> 5;
    int p = (blockIdx.x & 31) * 256 + threadIdx.x;
    int base = t * BATCH + p;

    float scale = GEO[12*TP + base];
    unsigned long long alive = __ballot(scale != 0.f);
    if (alive == 0ULL) { contrib[base] = 0.f; return; }

    float inp[6], coef[6];
    #pragma unroll
    for (int i = 0; i < 6; ++i) inp[i]  = GEO[i*TP + base];
    #pragma unroll
    for (int i = 0; i < 6; ++i) coef[i] = GEO[(6 + i)*TP + base];
    int meta = ((const int*)GEO)[13*TP + base];
    int r = meta & 255, sa = (meta >> 8) & 255;
    float jflag = (float)((meta >> 16) & 1);

    // ---- h-net L1 ----
    float h1[64];
    {
        const float* w1t = ws + OFF_W1T + t*512;
        #pragma unroll
        for (int j = 0; j < 64; ++j) {
            const float* w = w1t + j*8;
            float a = w[6];
            #pragma unroll
            for (int i = 0; i < 6; ++i) a = fmaf(inp[i], w[i], a);
            h1[j] = tanh_f(a);
        }
    }
    // ---- h-net L2 + W3E fold ----
    float gup[6] = {0.f, 0.f, 0.f, 0.f, 0.f, 0.f};
    {
        const float* w2t = ws + OFF_W2T + t*4096;
        const float* w3e = ws + OFF_W3E + (size_t)((t*11 + r)*64)*8;
        const float* b2t = b2 + t*64;
        #pragma unroll 2
        for (int cc = 0; cc < 64; ++cc) {
            float4 g0 = *(const float4*)(w3e + cc*8);
            float4 g1 = *(const float4*)(w3e + cc*8 + 4);
            const float* wr = w2t + cc*64;
            float a0 = b2t[cc], a1 = 0.f, a2 = 0.f, a3 = 0.f;
            #pragma unroll
            for (int k = 0; k < 64; k += 4) {
                a0 = fmaf(h1[k],   wr[k],   a0);
                a1 = fmaf(h1[k+1], wr[k+1], a1);
                a2 = fmaf(h1[k+2], wr[k+2], a2);
                a3 = fmaf(h1[k+3], wr[k+3], a3);
            }
            float h2 = tanh_f((a0 + a1) + (a2 + a3));
            gup[0] = fmaf(h2, g0.x, gup[0]);
            gup[1] = fmaf(h2, g0.y, gup[1]);
            gup[2] = fmaf(h2, g0.z, gup[2]);
            gup[3] = fmaf(h2, g0.w, gup[3]);
            gup[4] = fmaf(h2, g1.x, gup[4]);
            gup[5] = fmaf(h2, g1.y, gup[5]);
        }
        // bias row of emb-contraction
        const float4* bp = (const float4*)(ws + OFF_B3E + (t*11 + r)*8);
        float4 bb0 = bp[0], bb1 = bp[1];
        gup[0] += bb0.x; gup[1] += bb0.y; gup[2] += bb0.z;
        gup[3] += bb0.w; gup[4] += bb1.x; gup[5] += bb1.y;
    }
    // ---- f-net L1 ----
    float f1[64];
    {
        const float* w1t = ws + OFF_WF1T + t*512;
        #pragma unroll
        for (int j = 0; j < 64; ++j) {
            const float* w = w1t + j*8;
            float a = w[6];
            #pragma unroll
            for (int i = 0; i < 6; ++i) a = fmaf(inp[i], w[i], a);
            f1[j] = tanh_f(a);
        }
    }
    // ---- f-net L2 + CT/BT fold ----
    float hc = 0.f, hb = 0.f;
    {
        const float* wf2t = ws + OFF_WF2T + t*4096;
        const float* ctp = ws + OFF_CT + (size_t)(t*11 + r)*64;
        const float* btp = ws + OFF_BT + ((size_t)(t*11 + r)*20 + sa)*64;
        const float* bf2t = bf2 + t*64;
        #pragma unroll 1
        for (int c4 = 0; c4 < 16; ++c4) {
            float4 ctv = *(const float4*)(ctp + c4*4);
            float4 btv = *(const float4*)(btp + c4*4);
            float h2v[4];
            #pragma unroll
            for (int q = 0; q < 4; ++q) {
                int cc = c4*4 + q;
                const float* wr = wf2t + cc*64;
                float a0 = bf2t[cc], a1 = 0.f, a2 = 0.f, a3 = 0.f;
                #pragma unroll
                for (int k = 0; k < 64; k += 4) {
                    a0 = fmaf(f1[k],   wr[k],   a0);
                    a1 = fmaf(f1[k+1], wr[k+1], a1);
                    a2 = fmaf(f1[k+2], wr[k+2], a2);
                    a3 = fmaf(f1[k+3], wr[k+3], a3);
                }
                h2v[q] = tanh_f((a0 + a1) + (a2 + a3));
            }
            hc = fmaf(h2v[0], ctv.x, hc); hc = fmaf(h2v[1], ctv.y, hc);
            hc = fmaf(h2v[2], ctv.z, hc); hc = fmaf(h2v[3], ctv.w, hc);
            hb = fmaf(h2v[0], btv.x, hb); hb = fmaf(h2v[1], btv.y, hb);
            hb = fmaf(h2v[2], btv.z, hb); hb = fmaf(h2v[3], btv.w, hb);
        }
    }
    float jbias = jflag * ws[OFF_BB + (t*11 + r)*20 + sa] - DT * ws[OFF_BC + t*11 + r];
    float dpart = jflag*hb - DT*hc + jbias;
    #pragma unroll
    for (int o = 0; o < 6; ++o) dpart = fmaf(gup[o], coef[o], dpart);
    contrib[base] = scale * dpart;
}

// ---- K6: reduce over t ----------------------------------------------------
__global__ void k_reduce(const float* __restrict__ contrib, const float* __restrict__ u,
                         float* out) {
    int g = blockIdx.x * 256 + threadIdx.x;
    float a = u[0];
    #pragma unroll
    for (int t = 0; t < NSTEP; ++t) a += contrib[t*BATCH + g];
    out[g] = a;
}

extern "C" void kernel_launch(void* const* d_in, const int* in_sizes, int n_in,
                              void* d_out, int out_size, void* d_ws, size_t ws_size,
                              hipStream_t stream) {
    const float* u      = (const float*)d_in[0];
    const float* jump_r = (const float*)d_in[1];
    const float* jump_l = (const float*)d_in[2];
    const float* W1  = (const float*)d_in[3];
    const float* b1  = (const float*)d_in[4];
    const float* W2  = (const float*)d_in[5];
    const float* b2  = (const float*)d_in[6];
    const float* W3  = (const float*)d_in[7];
    const float* b3  = (const float*)d_in[8];
    const float* emb = (const float*)d_in[9];
    const float* Wf1 = (const float*)d_in[10];
    const float* bf1 = (const float*)d_in[11];
    const float* Wf2 = (const float*)d_in[12];
    const float* bf2 = (const float*)d_in[13];
    const float* Wf3 = (const float*)d_in[14];
    const float* bf3 = (const float*)d_in[15];
    const int*   rt0 = (const int*)d_in[16];
    const float* xt0 = (const float*)d_in[17];
    const float* yt0 = (const float*)d_in[18];
    const float* dBx = (const float*)d_in[19];
    const float* dBy = (const float*)d_in[20];
    const float* junif = (const float*)d_in[21];
    const float* sunif = (const float*)d_in[22];
    const float* mcu = (const float*)d_in[23];
    const float* jm  = (const float*)d_in[24];
    const float* cr  = (const float*)d_in[25];
    const float* cfr = (const float*)d_in[26];
    float* ws  = (float*)d_ws;
    float* out = (float*)d_out;

    hipMemsetAsync(ws + OFF_HIST, 0, 220*sizeof(int), stream);
    k_geom<<<32, 256, 0, stream>>>(rt0, xt0, yt0, dBx, dBy, junif, sunif,
                                   jm, cr, cfr, ws + OFF_GEO, out);
    k_hist<<<430, 256, 0, stream>>>(mcu, jm, (int*)(ws + OFF_HIST));
    k_mcj<<<6, 256, 0, stream>>>((const int*)(ws + OFF_HIST), jump_l, cr, ws + OFF_MCJ);
    k_tables<<<64*65, 256, 0, stream>>>(W3, b3, emb, Wf3, bf3, jump_r, jump_l,
                                        ws + OFF_MCJ, ws);
    k_wt<<<64, 256, 0, stream>>>(W1, b1, Wf1, bf1, W2, Wf2, ws);
    k_mlp<<<2048, 256, 0, stream>>>(ws, b2, bf2, ws + OFF_GEO, ws + OFF_CONTRIB);
    k_reduce<<<32, 256, 0, stream>>>(ws + OFF_CONTRIB, u, out);
}

// Round 4
// 582.604 us; speedup vs baseline: 3.4965x; 1.0641x over previous
//
#include <hip/hip_runtime.h>
#include <math.h>

#define NUMR 11
#define NSTEP 64
#define BATCH 8192
#define PDIM 128
#define MC 10000
#define DT (1.0f/64.0f)
#define RDOM 5.0f
#define CAP_EPS 0.1f
#define TP (NSTEP*BATCH)        // 524288

// workspace float offsets (total 9782848 floats = ~39.1 MB)
#define OFF_HIST 0              // 220 ints
#define OFF_MCJ  256            // 11*128 = 1408
#define OFF_W3E  1664           // [t][r][k*8+o(6 used)] 64*11*512 = 360448
#define OFF_B3E  362112         // [t][r][8]             64*11*8   = 5632
#define OFF_BT   367744         // [t][r][sa][k]         64*11*20*64 = 901120
#define OFF_BB   1268864        // [t][r][sa]            14080
#define OFF_CT   1282944        // [t][r][k]             45056
#define OFF_BC   1328000        // [t][r]                704
#define OFF_GEO  1328704        // 14 fields x [t][p] = 14*524288 = 7340032
#define OFF_CONTRIB 8668736     // [t][p] 524288
#define OFF_W2T  9193024        // [t][c][k] 262144
#define OFF_WF2T 9455168        // 262144
#define OFF_W1T  9717312        // [t][j][8] = {W1[0..5][j], b1[j], 0} 32768
#define OFF_WF1T 9750080        // 32768

__device__ __forceinline__ float tanh_f(float x) {
    float e = __expf(2.0f * x);
    return 1.0f - 2.0f * __builtin_amdgcn_rcpf(e + 1.0f);
}

__device__ __forceinline__ void reflect3(float* p, float* g) {
    float nr = sqrtf(p[0]*p[0] + p[1]*p[1] + p[2]*p[2]);
    if (nr > RDOM) {
        float inv = 1.0f / fmaxf(nr, 1e-12f);
        float nb0 = p[0]*inv, nb1 = p[1]*inv, nb2 = p[2]*inv;
        float sc = 2.0f*RDOM - nr;
        p[0] = nb0*sc; p[1] = nb1*sc; p[2] = nb2*sc;
        #pragma unroll
        for (int j = 0; j < 3; ++j) {
            float proj = nb0*g[j] + nb1*g[3+j] + nb2*g[6+j];
            g[j]   -= 2.0f*nb0*proj;
            g[3+j] -= 2.0f*nb1*proj;
            g[6+j] -= 2.0f*nb2*proj;
        }
    }
}

// ---- K1: histogram of MC jump sizes per (r, sa) --------------------------
__global__ void k_hist(const float* __restrict__ mcu, const float* __restrict__ jm,
                       int* hist) {
    __shared__ int lh[220];
    int tid = threadIdx.x;
    for (int i = tid; i < 220; i += 256) lh[i] = 0;
    __syncthreads();
    int i = blockIdx.x * 256 + tid;
    if (i < MC * NUMR) {
        int r = i % NUMR;
        float u = mcu[i];
        int cnt = 0;
        #pragma unroll
        for (int j = 0; j < 20; ++j) cnt += (u < jm[r*20 + j]) ? 1 : 0;
        int ind = 20 - cnt;
        int s = (ind < 10) ? (ind + 1) : -(ind - 9);
        int sa = (s > 0) ? (s - 1) : (10 + (-s - 1));
        atomicAdd(&lh[r*20 + sa], 1);
    }
    __syncthreads();
    for (int q = tid; q < 220; q += 256) if (lh[q]) atomicAdd(&hist[q], lh[q]);
}

// ---- K2: mc_jump[r][p] ----------------------------------------------------
__global__ void k_mcj(const int* hist, const float* __restrict__ jl,
                      const float* __restrict__ cr, float* mcj) {
    int i = blockIdx.x * 256 + threadIdx.x;
    if (i >= NUMR * PDIM) return;
    int r = i / PDIM, p = i % PDIM;
    float acc = 0.f;
    #pragma unroll
    for (int sa = 0; sa < 20; ++sa)
        acc += (float)hist[r*20 + sa] * jl[sa*PDIM + p];
    mcj[r*PDIM + p] = acc * cr[r] * (1.0f / (float)MC);
}

// ---- K3: per-step contraction tables -------------------------------------
__global__ void k_tables(const float* __restrict__ W3, const float* __restrict__ b3,
                         const float* __restrict__ emb, const float* __restrict__ Wf3,
                         const float* __restrict__ bf3, const float* __restrict__ jump_r,
                         const float* __restrict__ jl, const float* __restrict__ mcj,
                         float* ws) {
    int t  = blockIdx.x / 65;
    int kk = blockIdx.x % 65;
    bool brow = (kk == 64);
    const float* w3row = brow ? (b3 + t*768) : (W3 + (t*64 + kk)*768);
    const float* wfrow = brow ? (bf3 + t*128) : (Wf3 + (t*64 + kk)*128);
    for (int q = threadIdx.x; q < 297; q += blockDim.x) {
        if (q < 66) {
            int o = q / 11, r = q % 11;
            const float* e = emb + (t*11 + r)*128;
            float a0 = 0.f, a1 = 0.f;
            #pragma unroll 4
            for (int p = 0; p < 128; p += 2) {
                a0 = fmaf(e[p],   w3row[p*6 + o],     a0);
                a1 = fmaf(e[p+1], w3row[(p+1)*6 + o], a1);
            }
            float acc = a0 + a1;
            if (brow) ws[OFF_B3E + (t*11 + r)*8 + o] = acc;
            else      ws[OFF_W3E + (size_t)((t*11 + r)*64 + kk)*8 + o] = acc;
        } else if (q < 77) {
            int r = q - 66;
            float a0 = 0.f, a1 = 0.f;
            #pragma unroll 4
            for (int p = 0; p < 128; p += 2) {
                a0 = fmaf(wfrow[p],   jump_r[r*128 + p]   * mcj[r*128 + p],   a0);
                a1 = fmaf(wfrow[p+1], jump_r[r*128 + p+1] * mcj[r*128 + p+1], a1);
            }
            float acc = a0 + a1;
            if (brow) ws[OFF_BC + t*11 + r] = acc;
            else      ws[OFF_CT + (t*11 + r)*64 + kk] = acc;
        } else {
            int qq = q - 77;
            int sa = qq / 11, r = qq % 11;
            float a0 = 0.f, a1 = 0.f;
            #pragma unroll 4
            for (int p = 0; p < 128; p += 2) {
                a0 = fmaf(wfrow[p],   jump_r[r*128 + p]   * jl[sa*128 + p],   a0);
                a1 = fmaf(wfrow[p+1], jump_r[r*128 + p+1] * jl[sa*128 + p+1], a1);
            }
            float acc = a0 + a1;
            if (brow) ws[OFF_BB + (t*11 + r)*20 + sa] = acc;
            else      ws[OFF_BT + ((size_t)(t*11 + r)*20 + sa)*64 + kk] = acc;
        }
    }
}

// ---- K3b: weight transposes ----------------------------------------------
__global__ void k_wt(const float* __restrict__ W1, const float* __restrict__ b1,
                     const float* __restrict__ Wf1, const float* __restrict__ bf1,
                     const float* __restrict__ W2, const float* __restrict__ Wf2,
                     float* ws) {
    int t = blockIdx.x, tid = threadIdx.x;
    for (int i = tid; i < 4096; i += 256) {
        int k = i >> 6, c = i & 63;
        ws[OFF_W2T  + t*4096 + c*64 + k] = W2[t*4096 + k*64 + c];
        ws[OFF_WF2T + t*4096 + c*64 + k] = Wf2[t*4096 + k*64 + c];
    }
    for (int i = tid; i < 512; i += 256) {
        int j = i >> 3, o = i & 7;
        float v  = (o < 6) ? W1[t*384 + o*64 + j]  : ((o == 6) ? b1[t*64 + j]  : 0.f);
        float vf = (o < 6) ? Wf1[t*384 + o*64 + j] : ((o == 6) ? bf1[t*64 + j] : 0.f);
        ws[OFF_W1T  + t*512 + i] = v;
        ws[OFF_WF1T + t*512 + i] = vf;
    }
}

// ---- K4: trajectory (sequential part only) -------------------------------
__launch_bounds__(256)
__global__ void k_geom(const int* __restrict__ rt0, const float* __restrict__ xt0,
                       const float* __restrict__ yt0, const float* __restrict__ dBx,
                       const float* __restrict__ dBy, const float* __restrict__ junif,
                       const float* __restrict__ sunif, const float* __restrict__ jm,
                       const float* __restrict__ cr, const float* __restrict__ cfr,
                       float* GEO, int* hist, float* out) {
    __shared__ float sjm[220], scr[11], scfr[11];
    int tid = threadIdx.x;
    // zero the MC histogram here (k_hist runs stream-later) — saves a memset dispatch
    if (blockIdx.x == 0 && tid < 220) hist[tid] = 0;
    for (int i = tid; i < 220; i += 256) sjm[i] = jm[i];
    if (tid < 11) { scr[tid] = cr[tid]; scfr[tid] = cfr[tid]; }
    __syncthreads();
    int p = blockIdx.x * 256 + tid;

    int rt = rt0[p];
    float xt[3], xin[3], yin[3], gtx[9], gty[9];
    #pragma unroll
    for (int i = 0; i < 3; ++i) { xt[i] = xt0[p*3 + i]; xin[i] = xt[i]; yin[i] = yt0[p*3 + i]; }
    #pragma unroll
    for (int i = 0; i < 9; ++i) { gtx[i] = (i % 4 == 0) ? 1.f : 0.f; gty[i] = gtx[i]; }
    float fun = 0.f, run = 1.f;

    float ju = junif[p], su = sunif[p];
    float dbx0 = dBx[(size_t)p*2], dbx1 = dBx[(size_t)p*2 + 1];
    float dby0 = dBy[(size_t)p*3], dby1 = dBy[(size_t)p*3 + 1], dby2 = dBy[(size_t)p*3 + 2];

    int* GEOi = (int*)GEO;
    #pragma unroll 1
    for (int t = 0; t < NSTEP; ++t) {
        float nju = 0.f, nsu = 0.f, ndbx0 = 0.f, ndbx1 = 0.f, ndby0 = 0.f, ndby1 = 0.f, ndby2 = 0.f;
        if (t < NSTEP - 1) {
            int nb = (t + 1) * BATCH + p;
            nju = junif[nb]; nsu = sunif[nb];
            ndbx0 = dBx[(size_t)nb*2]; ndbx1 = dBx[(size_t)nb*2 + 1];
            ndby0 = dBy[(size_t)nb*3]; ndby1 = dBy[(size_t)nb*3 + 1]; ndby2 = dBy[(size_t)nb*3 + 2];
        }
        int base = t * BATCH + p;
        int r = rt - 10;
        int jon = (ju < scr[r] * DT) ? 1 : 0;
        int cnt = 0;
        #pragma unroll
        for (int j = 0; j < 20; ++j) cnt += (su < sjm[r*20 + j]) ? 1 : 0;
        int ind = 20 - cnt;
        int drt = (ind < 10) ? (ind + 1) : -(ind - 9);
        drt = jon ? drt : 0;
        int sa = (drt > 0) ? (drt - 1) : ((drt < 0) ? (9 - drt) : 0);
        int jf = (drt != 0) ? 1 : 0;

        float nx = fmaxf(sqrtf(xt[0]*xt[0] + xt[1]*xt[1] + xt[2]*xt[2]), 1e-12f);
        float c = fminf(1.f, fmaxf(-1.f, xt[2] / nx));
        float ct = sqrtf(fmaxf(0.f, 1.f - c*c));
        float st = -c;
        float rxy2 = xt[0]*xt[0] + xt[1]*xt[1];
        float cp = 1.f, sp = 0.f;
        if (rxy2 > 0.f) { float ir = 1.0f / sqrtf(rxy2); cp = xt[0]*ir; sp = xt[1]*ir; }
        float Ti[9];
        Ti[0] = cp*ct; Ti[1] = -sp; Ti[2] = cp*st;
        Ti[3] = sp*ct; Ti[4] = cp;  Ti[5] = sp*st;
        Ti[6] = -st;   Ti[7] = 0.f; Ti[8] = ct;

        float sdx = 1.0f / (float)(r + 10);
        float scale = run * __expf(-fun);

        #pragma unroll
        for (int i = 0; i < 3; ++i) {
            GEO[i*TP + base]       = xin[i];
            GEO[(3 + i)*TP + base] = yin[i];
        }
        #pragma unroll
        for (int i = 0; i < 3; ++i) {
            float w31 = gtx[i*3]*Ti[1] + gtx[i*3+1]*Ti[4] + gtx[i*3+2]*Ti[7];
            float w32 = gtx[i*3]*Ti[2] + gtx[i*3+1]*Ti[5] + gtx[i*3+2]*Ti[8];
            GEO[(6 + i)*TP + base] = sdx * (w31*dbx1 - w32*dbx0);
            GEO[(9 + i)*TP + base] = gty[i*3]*dby0 + gty[i*3+1]*dby1 + gty[i*3+2]*dby2;
        }
        GEO[12*TP + base]  = scale;
        GEOi[13*TP + base] = r | (sa << 8) | (jf << 16);

        fun += scfr[r] * DT;

        float dX0 = sdx*dbx0, dX1 = sdx*dbx1;
        float s0 = __sinf(dX0), cc0 = __cosf(dX0);
        float s1 = __sinf(dX1), cc1 = __cosf(dX1);
        float cart0 = cc0*cc1 - 1.0f, cart1 = cc0*s1, cart2 = -s0;
        float dX3[3];
        #pragma unroll
        for (int i = 0; i < 3; ++i)
            dX3[i] = Ti[i*3]*cart0 + Ti[i*3+1]*cart1 + Ti[i*3+2]*cart2;
        #pragma unroll
        for (int i = 0; i < 3; ++i) xt[i] += dX3[i];
        #pragma unroll
        for (int i = 0; i < 3; ++i)
            xin[i] += gtx[i*3]*dX3[0] + gtx[i*3+1]*dX3[1] + gtx[i*3+2]*dX3[2];
        #pragma unroll
        for (int i = 0; i < 3; ++i)
            yin[i] += gty[i*3]*dby0 + gty[i*3+1]*dby1 + gty[i*3+2]*dby2;
        rt += drt; rt = (rt < 10) ? 10 : ((rt > 20) ? 20 : rt);
        reflect3(xin, gtx);
        reflect3(yin, gty);
        float d0 = xin[0]-yin[0], d1 = xin[1]-yin[1], d2 = xin[2]-yin[2];
        if (sqrtf(d0*d0 + d1*d1 + d2*d2) < CAP_EPS) run = 0.f;

        ju = nju; su = nsu; dbx0 = ndbx0; dbx1 = ndbx1;
        dby0 = ndby0; dby1 = ndby1; dby2 = ndby2;
    }
    float d0 = xin[0]-yin[0], d1 = xin[1]-yin[1], d2 = xin[2]-yin[2];
    float u0v = __expf(-(d0*d0 + d1*d1 + d2*d2));
    out[BATCH + p] = run * u0v * __expf(-fun);
}

// ---- K5: batched MLP; per-t weights staged in LDS -------------------------
// t = blockIdx & 63 so co-resident blocks (b ≡ cu mod 256) share t: staging
// and table gathers stay L2/L1-local; kills the sK$ thrash seen in R3.
__launch_bounds__(256, 4)
__global__ void k_mlp(const float* __restrict__ ws, const float* __restrict__ b2,
                      const float* __restrict__ bf2,
                      const float* __restrict__ GEO, float* __restrict__ contrib) {
    __shared__ float sW2h[4096], sW2f[4096];
    __shared__ float sW1h[512],  sW1f[512];
    __shared__ float sB2[64],    sBf2[64];

    int tid = threadIdx.x;
    int t = blockIdx.x & 63;
    int p = (blockIdx.x >> 6) * 256 + tid;
    int base = t * BATCH + p;

    {
        const float* g2h = ws + OFF_W2T  + t*4096;
        const float* g2f = ws + OFF_WF2T + t*4096;
        #pragma unroll
        for (int i = 0; i < 16; ++i) {
            sW2h[i*256 + tid] = g2h[i*256 + tid];
            sW2f[i*256 + tid] = g2f[i*256 + tid];
        }
        const float* g1h = ws + OFF_W1T  + t*512;
        const float* g1f = ws + OFF_WF1T + t*512;
        #pragma unroll
        for (int i = 0; i < 2; ++i) {
            sW1h[i*256 + tid] = g1h[i*256 + tid];
            sW1f[i*256 + tid] = g1f[i*256 + tid];
        }
        if (tid < 64)  sB2[tid] = b2[t*64 + tid];
        else if (tid < 128) sBf2[tid - 64] = bf2[t*64 + tid - 64];
    }
    __syncthreads();

    float scale = GEO[12*TP + base];
    float inp[6], coef[6];
    #pragma unroll
    for (int i = 0; i < 6; ++i) inp[i]  = GEO[i*TP + base];
    #pragma unroll
    for (int i = 0; i < 6; ++i) coef[i] = GEO[(6 + i)*TP + base];
    int meta = ((const int*)GEO)[13*TP + base];
    int r = meta & 255, sa = (meta >> 8) & 255;
    float jflag = (float)((meta >> 16) & 1);

    // ---- h-net L1 (weights broadcast from LDS) ----
    float h1[64];
    #pragma unroll
    for (int j = 0; j < 64; ++j) {
        float4 wa = *(const float4*)(sW1h + j*8);
        float4 wb = *(const float4*)(sW1h + j*8 + 4);
        float a = wb.z;
        a = fmaf(inp[0], wa.x, a); a = fmaf(inp[1], wa.y, a);
        a = fmaf(inp[2], wa.z, a); a = fmaf(inp[3], wa.w, a);
        a = fmaf(inp[4], wb.x, a); a = fmaf(inp[5], wb.y, a);
        h1[j] = tanh_f(a);
    }
    // ---- h-net L2 + W3E fold ----
    float gup[6] = {0.f, 0.f, 0.f, 0.f, 0.f, 0.f};
    {
        const float* w3e = ws + OFF_W3E + (size_t)((t*11 + r)*64)*8;
        #pragma unroll 2
        for (int cc = 0; cc < 64; ++cc) {
            float4 g0 = *(const float4*)(w3e + cc*8);
            float4 g1 = *(const float4*)(w3e + cc*8 + 4);
            const float4* wr = (const float4*)(sW2h + cc*64);
            float a0 = sB2[cc], a1 = 0.f, a2 = 0.f, a3 = 0.f;
            #pragma unroll
            for (int k4 = 0; k4 < 16; ++k4) {
                float4 wv = wr[k4];
                a0 = fmaf(h1[k4*4],   wv.x, a0);
                a1 = fmaf(h1[k4*4+1], wv.y, a1);
                a2 = fmaf(h1[k4*4+2], wv.z, a2);
                a3 = fmaf(h1[k4*4+3], wv.w, a3);
            }
            float h2 = tanh_f((a0 + a1) + (a2 + a3));
            gup[0] = fmaf(h2, g0.x, gup[0]);
            gup[1] = fmaf(h2, g0.y, gup[1]);
            gup[2] = fmaf(h2, g0.z, gup[2]);
            gup[3] = fmaf(h2, g0.w, gup[3]);
            gup[4] = fmaf(h2, g1.x, gup[4]);
            gup[5] = fmaf(h2, g1.y, gup[5]);
        }
        const float4* bp = (const float4*)(ws + OFF_B3E + (t*11 + r)*8);
        float4 bb0 = bp[0], bb1 = bp[1];
        gup[0] += bb0.x; gup[1] += bb0.y; gup[2] += bb0.z;
        gup[3] += bb0.w; gup[4] += bb1.x; gup[5] += bb1.y;
    }
    // ---- f-net L1 ----
    float f1[64];
    #pragma unroll
    for (int j = 0; j < 64; ++j) {
        float4 wa = *(const float4*)(sW1f + j*8);
        float4 wb = *(const float4*)(sW1f + j*8 + 4);
        float a = wb.z;
        a = fmaf(inp[0], wa.x, a); a = fmaf(inp[1], wa.y, a);
        a = fmaf(inp[2], wa.z, a); a = fmaf(inp[3], wa.w, a);
        a = fmaf(inp[4], wb.x, a); a = fmaf(inp[5], wb.y, a);
        f1[j] = tanh_f(a);
    }
    // ---- f-net L2 + CT/BT fold ----
    float hc = 0.f, hb = 0.f;
    {
        const float* ctp = ws + OFF_CT + (size_t)(t*11 + r)*64;
        const float* btp = ws + OFF_BT + ((size_t)(t*11 + r)*20 + sa)*64;
        #pragma unroll 1
        for (int c4 = 0; c4 < 16; ++c4) {
            float4 ctv = *(const float4*)(ctp + c4*4);
            float4 btv = *(const float4*)(btp + c4*4);
            float h2v[4];
            #pragma unroll
            for (int q = 0; q < 4; ++q) {
                int cc = c4*4 + q;
                const float4* wr = (const float4*)(sW2f + cc*64);
                float a0 = sBf2[cc], a1 = 0.f, a2 = 0.f, a3 = 0.f;
                #pragma unroll
                for (int k4 = 0; k4 < 16; ++k4) {
                    float4 wv = wr[k4];
                    a0 = fmaf(f1[k4*4],   wv.x, a0);
                    a1 = fmaf(f1[k4*4+1], wv.y, a1);
                    a2 = fmaf(f1[k4*4+2], wv.z, a2);
                    a3 = fmaf(f1[k4*4+3], wv.w, a3);
                }
                h2v[q] = tanh_f((a0 + a1) + (a2 + a3));
            }
            hc = fmaf(h2v[0], ctv.x, hc); hc = fmaf(h2v[1], ctv.y, hc);
            hc = fmaf(h2v[2], ctv.z, hc); hc = fmaf(h2v[3], ctv.w, hc);
            hb = fmaf(h2v[0], btv.x, hb); hb = fmaf(h2v[1], btv.y, hb);
            hb = fmaf(h2v[2], btv.z, hb); hb = fmaf(h2v[3], btv.w, hb);
        }
    }
    float jbias = jflag * ws[OFF_BB + (t*11 + r)*20 + sa] - DT * ws[OFF_BC + t*11 + r];
    float dpart = jflag*hb - DT*hc + jbias;
    #pragma unroll
    for (int o = 0; o < 6; ++o) dpart = fmaf(gup[o], coef[o], dpart);
    contrib[base] = scale * dpart;
}

// ---- K6: reduce over t ----------------------------------------------------
__global__ void k_reduce(const float* __restrict__ contrib, const float* __restrict__ u,
                         float* out) {
    int g = blockIdx.x * 256 + threadIdx.x;
    float a = u[0];
    #pragma unroll
    for (int t = 0; t < NSTEP; ++t) a += contrib[t*BATCH + g];
    out[g] = a;
}

extern "C" void kernel_launch(void* const* d_in, const int* in_sizes, int n_in,
                              void* d_out, int out_size, void* d_ws, size_t ws_size,
                              hipStream_t stream) {
    const float* u      = (const float*)d_in[0];
    const float* jump_r = (const float*)d_in[1];
    const float* jump_l = (const float*)d_in[2];
    const float* W1  = (const float*)d_in[3];
    const float* b1  = (const float*)d_in[4];
    const float* W2  = (const float*)d_in[5];
    const float* b2  = (const float*)d_in[6];
    const float* W3  = (const float*)d_in[7];
    const float* b3  = (const float*)d_in[8];
    const float* emb = (const float*)d_in[9];
    const float* Wf1 = (const float*)d_in[10];
    const float* bf1 = (const float*)d_in[11];
    const float* Wf2 = (const float*)d_in[12];
    const float* bf2 = (const float*)d_in[13];
    const float* Wf3 = (const float*)d_in[14];
    const float* bf3 = (const float*)d_in[15];
    const int*   rt0 = (const int*)d_in[16];
    const float* xt0 = (const float*)d_in[17];
    const float* yt0 = (const float*)d_in[18];
    const float* dBx = (const float*)d_in[19];
    const float* dBy = (const float*)d_in[20];
    const float* junif = (const float*)d_in[21];
    const float* sunif = (const float*)d_in[22];
    const float* mcu = (const float*)d_in[23];
    const float* jm  = (const float*)d_in[24];
    const float* cr  = (const float*)d_in[25];
    const float* cfr = (const float*)d_in[26];
    float* ws  = (float*)d_ws;
    float* out = (float*)d_out;

    k_geom<<<32, 256, 0, stream>>>(rt0, xt0, yt0, dBx, dBy, junif, sunif,
                                   jm, cr, cfr, ws + OFF_GEO,
                                   (int*)(ws + OFF_HIST), out);
    k_hist<<<430, 256, 0, stream>>>(mcu, jm, (int*)(ws + OFF_HIST));
    k_mcj<<<6, 256, 0, stream>>>((const int*)(ws + OFF_HIST), jump_l, cr, ws + OFF_MCJ);
    k_tables<<<64*65, 256, 0, stream>>>(W3, b3, emb, Wf3, bf3, jump_r, jump_l,
                                        ws + OFF_MCJ, ws);
    k_wt<<<64, 256, 0, stream>>>(W1, b1, Wf1, bf1, W2, Wf2, ws);
    k_mlp<<<2048, 256, 0, stream>>>(ws, b2, bf2, ws + OFF_GEO, ws + OFF_CONTRIB);
    k_reduce<<<32, 256, 0, stream>>>(ws + OFF_CONTRIB, u, out);
}